// Round 2
// baseline (441.269 us; speedup 1.0000x reference)
//
#include <hip/hip_runtime.h>
#include <hip/hip_bf16.h>

// GCN 2-layer forward. N=50000 nodes, E=800000 edges, F=128, H=128, C=64.
//   deg[v] = indeg(v)+1 ; dinv = rsqrt(deg)
//   y1 = (x @ W1) * dinv[row]
//   h  = relu(dinv[v]*(sum_{e: dst=v} y1[src] + y1[v]) + b1)
//   y2 = (h @ W2) * dinv[row]
//   o  = dinv[v]*(sum y2[src] + y2[v]) + b2 ; out = log_softmax(o)
// norm = dinv[s]*dinv[d] factors into the GEMM epilogue (src side) and the
// aggregation epilogue (dst side); self-loop term is y[v] added in registers.

#define K_DIM 128

__global__ void count_kernel(const int* __restrict__ dst, int* __restrict__ deg, int E) {
    for (int e = blockIdx.x * blockDim.x + threadIdx.x; e < E; e += gridDim.x * blockDim.x)
        atomicAdd(&deg[dst[e]], 1);
}

__global__ void dinv_kernel(const int* __restrict__ deg, float* __restrict__ dinv, int n) {
    for (int i = blockIdx.x * blockDim.x + threadIdx.x; i < n; i += gridDim.x * blockDim.x)
        dinv[i] = rsqrtf((float)(deg[i] + 1));   // +1 self loop
}

// Single-block scan, thread-serial chunks + wave shfl scan. 2 barriers total.
// rowptr[0..n] = exclusive prefix of deg (rowptr[n]=E); fillpos[i]=rowptr[i].
__global__ __launch_bounds__(1024) void scan_kernel(const int* __restrict__ deg,
        int* __restrict__ rowptr, int* __restrict__ fillpos, int n) {
    const int tid = threadIdx.x;
    const int chunk = (n + 1023) >> 10;
    const int start = tid * chunk;
    const int end   = min(start + chunk, n);

    int sum = 0;
    for (int i = start; i < end; ++i) sum += deg[i];

    // inclusive scan of per-thread sums within each wave (64 lanes, no barrier)
    const int lane = tid & 63;
    const int wid  = tid >> 6;           // 0..15
    int s = sum;
    #pragma unroll
    for (int off = 1; off < 64; off <<= 1) {
        int t = __shfl_up(s, off);
        if (lane >= off) s += t;
    }

    __shared__ int wsum[16];
    __shared__ int woff[16];
    if (lane == 63) wsum[wid] = s;
    __syncthreads();
    if (tid < 16) {
        int v = wsum[tid];
        int sc = v;
        #pragma unroll
        for (int off = 1; off < 16; off <<= 1) {
            int t = __shfl_up(sc, off);
            if (tid >= off) sc += t;
        }
        woff[tid] = sc - v;              // exclusive wave offset
    }
    __syncthreads();

    int run = woff[wid] + (s - sum);     // exclusive prefix for this thread
    if (tid == 0) rowptr[0] = 0;
    for (int i = start; i < end; ++i) {
        int d = deg[i];
        fillpos[i] = run;
        run += d;
        rowptr[i + 1] = run;
    }
}

__global__ void fill_kernel(const int* __restrict__ src, const int* __restrict__ dst,
                            int* __restrict__ fillpos, int* __restrict__ csrc, int E) {
    for (int e = blockIdx.x * blockDim.x + threadIdx.x; e < E; e += gridDim.x * blockDim.x) {
        int p = atomicAdd(&fillpos[dst[e]], 1);
        csrc[p] = src[e];
    }
}

// Y[row] = (X[row] @ W) * dinv[row].  W [K][NOUT] row-major staged in LDS.
// Register tile: RPT rows x 4 cols per thread (all indices static).
template<int NOUT, int RPT>
__global__ __launch_bounds__(256) void gemm_scale(const float* __restrict__ X,
        const float* __restrict__ W, const float* __restrict__ dinv,
        float* __restrict__ Y, int nrows) {
    constexpr int K     = K_DIM;
    constexpr int CG    = NOUT / 4;      // col groups of 4 (32 or 16)
    constexpr int SLOTS = 256 / CG;      // row slots (8 or 16)
    constexpr int ROWS  = SLOTS * RPT;   // rows per block (32 or 64)
    __shared__ float Wl[K * NOUT];
    __shared__ float Xl[ROWS * K];
    const int tid = threadIdx.x;

    #pragma unroll
    for (int i = tid * 4; i < K * NOUT; i += 1024)
        *(float4*)&Wl[i] = *(const float4*)&W[i];

    const int row0 = blockIdx.x * ROWS;
    #pragma unroll
    for (int i = tid * 4; i < ROWS * K; i += 1024) {
        int gr = row0 + (i >> 7);
        float4 v = make_float4(0.f, 0.f, 0.f, 0.f);
        if (gr < nrows) v = *(const float4*)&X[(size_t)gr * K + (i & (K - 1))];
        *(float4*)&Xl[i] = v;
    }
    __syncthreads();

    const int col0 = (tid % CG) * 4;
    const int r0   = (tid / CG) * RPT;

    float acc[RPT][4];
    #pragma unroll
    for (int r = 0; r < RPT; ++r)
        #pragma unroll
        for (int c = 0; c < 4; ++c) acc[r][c] = 0.f;

    for (int k = 0; k < K; k += 4) {
        float4 w0 = *(const float4*)&Wl[(k + 0) * NOUT + col0];
        float4 w1 = *(const float4*)&Wl[(k + 1) * NOUT + col0];
        float4 w2 = *(const float4*)&Wl[(k + 2) * NOUT + col0];
        float4 w3 = *(const float4*)&Wl[(k + 3) * NOUT + col0];
        #pragma unroll
        for (int r = 0; r < RPT; ++r) {
            float4 xv = *(const float4*)&Xl[(r0 + r) * K + k];
            acc[r][0] += xv.x * w0.x + xv.y * w1.x + xv.z * w2.x + xv.w * w3.x;
            acc[r][1] += xv.x * w0.y + xv.y * w1.y + xv.z * w2.y + xv.w * w3.y;
            acc[r][2] += xv.x * w0.z + xv.y * w1.z + xv.z * w2.z + xv.w * w3.z;
            acc[r][3] += xv.x * w0.w + xv.y * w1.w + xv.z * w2.w + xv.w * w3.w;
        }
    }

    #pragma unroll
    for (int r = 0; r < RPT; ++r) {
        const int grow = row0 + r0 + r;
        if (grow < nrows) {
            float dv = dinv[grow];
            float4 o = make_float4(acc[r][0] * dv, acc[r][1] * dv,
                                   acc[r][2] * dv, acc[r][3] * dv);
            *(float4*)&Y[(size_t)grow * NOUT + col0] = o;
        }
    }
}

// Layer-1 aggregation: one wave per node, 128 feats = float2/lane.
// H[v] = relu(dinv[v]*(sum_in Y[u] + Y[v]) + b)
__global__ __launch_bounds__(256) void agg_relu128(const float* __restrict__ Y,
        const int* __restrict__ rowptr, const int* __restrict__ csrc,
        const float* __restrict__ dinv, const float* __restrict__ bias,
        float* __restrict__ H, int n) {
    const int lane = threadIdx.x & 63;
    const int v = blockIdx.x * 4 + (threadIdx.x >> 6);
    if (v >= n) return;
    const int s = rowptr[v], e = rowptr[v + 1];
    float ax = 0.f, ay = 0.f;
    int i = s;
    for (; i + 4 <= e; i += 4) {
        int u0 = csrc[i], u1 = csrc[i + 1], u2 = csrc[i + 2], u3 = csrc[i + 3];
        float2 a = *(const float2*)&Y[(size_t)u0 * 128 + lane * 2];
        float2 b = *(const float2*)&Y[(size_t)u1 * 128 + lane * 2];
        float2 c = *(const float2*)&Y[(size_t)u2 * 128 + lane * 2];
        float2 d = *(const float2*)&Y[(size_t)u3 * 128 + lane * 2];
        ax += a.x + b.x + c.x + d.x;
        ay += a.y + b.y + c.y + d.y;
    }
    for (; i < e; ++i) {
        int u = csrc[i];
        float2 a = *(const float2*)&Y[(size_t)u * 128 + lane * 2];
        ax += a.x; ay += a.y;
    }
    float2 yv = *(const float2*)&Y[(size_t)v * 128 + lane * 2];
    float2 bb = *(const float2*)&bias[lane * 2];
    float dv = dinv[v];
    float hx = dv * (ax + yv.x) + bb.x;
    float hy = dv * (ay + yv.y) + bb.y;
    float2 o = make_float2(fmaxf(hx, 0.f), fmaxf(hy, 0.f));
    *(float2*)&H[(size_t)v * 128 + lane * 2] = o;
}

// Layer-2 aggregation + bias + log_softmax: one wave per node, 64 feats = 1/lane.
__global__ __launch_bounds__(256) void agg_lsm64(const float* __restrict__ Y2,
        const int* __restrict__ rowptr, const int* __restrict__ csrc,
        const float* __restrict__ dinv, const float* __restrict__ bias,
        float* __restrict__ out, int n) {
    const int lane = threadIdx.x & 63;
    const int v = blockIdx.x * 4 + (threadIdx.x >> 6);
    if (v >= n) return;
    const int s = rowptr[v], e = rowptr[v + 1];
    float acc = 0.f;
    int i = s;
    for (; i + 4 <= e; i += 4) {
        int u0 = csrc[i], u1 = csrc[i + 1], u2 = csrc[i + 2], u3 = csrc[i + 3];
        acc += Y2[(size_t)u0 * 64 + lane] + Y2[(size_t)u1 * 64 + lane]
             + Y2[(size_t)u2 * 64 + lane] + Y2[(size_t)u3 * 64 + lane];
    }
    for (; i < e; ++i) acc += Y2[(size_t)csrc[i] * 64 + lane];
    float val = dinv[v] * (acc + Y2[(size_t)v * 64 + lane]) + bias[lane];
    // wave-wide (64 lanes = full class row) max and sum(exp)
    float m = val;
    #pragma unroll
    for (int off = 32; off >= 1; off >>= 1) m = fmaxf(m, __shfl_xor(m, off));
    float ex = expf(val - m);
    float ssum = ex;
    #pragma unroll
    for (int off = 32; off >= 1; off >>= 1) ssum += __shfl_xor(ssum, off);
    out[(size_t)v * 64 + lane] = val - m - logf(ssum);
}

static inline size_t align_up(size_t x, size_t a) { return (x + a - 1) & ~(a - 1); }

extern "C" void kernel_launch(void* const* d_in, const int* in_sizes, int n_in,
                              void* d_out, int out_size, void* d_ws, size_t ws_size,
                              hipStream_t stream) {
    const float* x  = (const float*)d_in[0];
    const int*   ei = (const int*)d_in[1];
    const float* W1 = (const float*)d_in[2];
    const float* b1 = (const float*)d_in[3];
    const float* W2 = (const float*)d_in[4];
    const float* b2 = (const float*)d_in[5];
    float* out = (float*)d_out;

    const int N = in_sizes[0] / 128;   // 50000
    const int E = in_sizes[1] / 2;     // 800000
    const int* src = ei;
    const int* dst = ei + E;

    // workspace layout (~56 MB)
    char* ws = (char*)d_ws;
    size_t off = 0;
    int* deg     = (int*)(ws + off); off = align_up(off + (size_t)N * 4, 512);
    int* rowptr  = (int*)(ws + off); off = align_up(off + (size_t)(N + 1) * 4, 512);
    int* fillpos = (int*)(ws + off); off = align_up(off + (size_t)N * 4, 512);
    float* dinv  = (float*)(ws + off); off = align_up(off + (size_t)N * 4, 512);
    int* csrc    = (int*)(ws + off); off = align_up(off + (size_t)E * 4, 512);
    float* y1    = (float*)(ws + off);                 // [N,128]; reused as y2 [N,64]
    size_t off_y1 = off; off = align_up(off + (size_t)N * 128 * 4, 512);
    float* h     = (float*)(ws + off); off = align_up(off + (size_t)N * 128 * 4, 512);
    float* y2    = (float*)(ws + off_y1);
    (void)ws_size; (void)n_in; (void)out_size;

    hipMemsetAsync(deg, 0, (size_t)N * 4, stream);

    count_kernel<<<2048, 256, 0, stream>>>(dst, deg, E);
    dinv_kernel<<<(N + 255) / 256, 256, 0, stream>>>(deg, dinv, N);
    scan_kernel<<<1, 1024, 0, stream>>>(deg, rowptr, fillpos, N);
    fill_kernel<<<2048, 256, 0, stream>>>(src, dst, fillpos, csrc, E);

    // layer 1: 32 rows/block
    gemm_scale<128, 4><<<(N + 31) / 32, 256, 0, stream>>>(x, W1, dinv, y1, N);
    agg_relu128<<<(N + 3) / 4, 256, 0, stream>>>(y1, rowptr, csrc, dinv, b1, h, N);

    // layer 2: 64 rows/block
    gemm_scale<64, 4><<<(N + 63) / 64, 256, 0, stream>>>(h, W2, dinv, y2, N);
    agg_lsm64<<<(N + 3) / 4, 256, 0, stream>>>(y2, rowptr, csrc, dinv, b2, out, N);
}

// Round 10
// 324.280 us; speedup vs baseline: 1.3608x; 1.3608x over previous
//
#include <hip/hip_runtime.h>
#include <hip/hip_bf16.h>

// GCN 2-layer forward. N=50000 nodes, E=800000 edges, F=128, H=128, C=64.
//   deg[v] = indeg(v)+1 ; dinv = rsqrt(deg)
//   y1 = (x @ W1) * dinv[row]
//   h  = relu(dinv[v]*(sum_{e: dst=v} y1[src] + y1[v]) + b1)
//   y2 = (h @ W2) * dinv[row]
//   o  = dinv[v]*(sum y2[src] + y2[v]) + b2 ; out = log_softmax(o)

#define K_DIM 128

__global__ void count_kernel(const int* __restrict__ dst, int* __restrict__ deg, int E) {
    for (int e = blockIdx.x * blockDim.x + threadIdx.x; e < E; e += gridDim.x * blockDim.x)
        atomicAdd(&deg[dst[e]], 1);
}

// ---- 3-phase parallel exclusive scan over deg[n] (tile = 1024 elems/block) ----
__global__ __launch_bounds__(256) void scan_phaseA(const int* __restrict__ deg,
        int* __restrict__ bsum, int n) {
    const int tid = threadIdx.x, lane = tid & 63, wid = tid >> 6;
    const int base = blockIdx.x * 1024 + tid * 4;
    int s = 0;
    if (base + 3 < n) {
        int4 t = *(const int4*)&deg[base];
        s = t.x + t.y + t.z + t.w;
    } else {
        for (int j = 0; j < 4; ++j) if (base + j < n) s += deg[base + j];
    }
    #pragma unroll
    for (int off = 32; off >= 1; off >>= 1) s += __shfl_xor(s, off);
    __shared__ int wtot[4];
    if (lane == 0) wtot[wid] = s;
    __syncthreads();
    if (tid == 0) bsum[blockIdx.x] = wtot[0] + wtot[1] + wtot[2] + wtot[3];
}

__global__ __launch_bounds__(64) void scan_phaseB(const int* __restrict__ bsum,
        int* __restrict__ boff, int nb) {
    const int lane = threadIdx.x;
    int carry = 0;
    for (int base = 0; base < nb; base += 64) {
        int i = base + lane;
        int v = (i < nb) ? bsum[i] : 0;
        int s = v;
        #pragma unroll
        for (int off = 1; off < 64; off <<= 1) {
            int t = __shfl_up(s, off);
            if (lane >= off) s += t;
        }
        if (i < nb) boff[i] = carry + s - v;
        carry += __shfl(s, 63);
    }
}

__global__ __launch_bounds__(256) void scan_phaseC(const int* __restrict__ deg,
        const int* __restrict__ boff, int* __restrict__ rowptr,
        int* __restrict__ fillpos, float* __restrict__ dinv, int n) {
    const int tid = threadIdx.x, lane = tid & 63, wid = tid >> 6;
    const int base = blockIdx.x * 1024 + tid * 4;
    int v0 = 0, v1 = 0, v2 = 0, v3 = 0;
    if (base + 3 < n) {
        int4 t = *(const int4*)&deg[base];
        v0 = t.x; v1 = t.y; v2 = t.z; v3 = t.w;
    } else {
        if (base     < n) v0 = deg[base];
        if (base + 1 < n) v1 = deg[base + 1];
        if (base + 2 < n) v2 = deg[base + 2];
        if (base + 3 < n) v3 = deg[base + 3];
    }
    const int s4 = v0 + v1 + v2 + v3;
    int incl = s4;
    #pragma unroll
    for (int off = 1; off < 64; off <<= 1) {
        int t = __shfl_up(incl, off);
        if (lane >= off) incl += t;
    }
    __shared__ int wtot[4];
    if (lane == 63) wtot[wid] = incl;
    __syncthreads();
    int wexc = 0;
    #pragma unroll
    for (int w = 0; w < 4; ++w) if (w < wid) wexc += wtot[w];

    const int ex = boff[blockIdx.x] + wexc + (incl - s4);
    if (blockIdx.x == 0 && tid == 0) rowptr[0] = 0;
    const int p1 = ex + v0, p2 = p1 + v1, p3 = p2 + v2, p4 = p3 + v3;
    if (base < n)     { fillpos[base]     = ex; rowptr[base + 1] = p1; dinv[base]     = rsqrtf((float)(v0 + 1)); }
    if (base + 1 < n) { fillpos[base + 1] = p1; rowptr[base + 2] = p2; dinv[base + 1] = rsqrtf((float)(v1 + 1)); }
    if (base + 2 < n) { fillpos[base + 2] = p2; rowptr[base + 3] = p3; dinv[base + 2] = rsqrtf((float)(v2 + 1)); }
    if (base + 3 < n) { fillpos[base + 3] = p3; rowptr[base + 4] = p4; dinv[base + 3] = rsqrtf((float)(v3 + 1)); }
}

__global__ void fill_kernel(const int* __restrict__ src, const int* __restrict__ dst,
                            int* __restrict__ fillpos, int* __restrict__ csrc, int E) {
    for (int e = blockIdx.x * blockDim.x + threadIdx.x; e < E; e += gridDim.x * blockDim.x) {
        int p = atomicAdd(&fillpos[dst[e]], 1);
        csrc[p] = src[e];
    }
}

// Y[row] = (X[row] @ W) * dinv[row].
// W [K][NOUT] staged in LDS (only operand staged; 0.5 B LDS per FLOP).
// X read from global: lanes sharing a row slot issue the same address (broadcast).
// Per thread: RPT rows x 8 cols, cols split as two float4 blocks at c0 and c0+NOUT/2
// (keeps the wave's ds_read_b128 pattern at 2-way bank aliasing = free).
template<int NOUT, int RPT>
__global__ __launch_bounds__(256) void gemm_scale(const float* __restrict__ X,
        const float* __restrict__ W, const float* __restrict__ dinv,
        float* __restrict__ Y, int nrows) {
    constexpr int K     = K_DIM;
    constexpr int CG    = NOUT / 8;       // col groups (8 cols per thread)
    constexpr int SLOTS = 256 / CG;       // row slots per block
    constexpr int ROWS  = SLOTS * RPT;    // rows per block
    constexpr int HALF  = NOUT / 2;
    __shared__ float Wl[K * NOUT];
    const int tid = threadIdx.x;

    #pragma unroll
    for (int i = tid * 4; i < K * NOUT; i += 1024)
        *(float4*)&Wl[i] = *(const float4*)&W[i];
    __syncthreads();

    const int cg = tid % CG, slot = tid / CG;
    const int c0 = cg * 4, c1 = c0 + HALF;
    const int row0 = blockIdx.x * ROWS + slot * RPT;

    int rIdx[RPT];
    #pragma unroll
    for (int r = 0; r < RPT; ++r) rIdx[r] = min(row0 + r, nrows - 1);

    float a0[RPT][4], a1[RPT][4];
    #pragma unroll
    for (int r = 0; r < RPT; ++r)
        #pragma unroll
        for (int c = 0; c < 4; ++c) { a0[r][c] = 0.f; a1[r][c] = 0.f; }

    #pragma unroll 2
    for (int k = 0; k < K; k += 4) {
        float4 xv[RPT];
        #pragma unroll
        for (int r = 0; r < RPT; ++r)
            xv[r] = *(const float4*)&X[(size_t)rIdx[r] * K + k];
        #pragma unroll
        for (int kk = 0; kk < 4; ++kk) {
            float4 wa = *(const float4*)&Wl[(k + kk) * NOUT + c0];
            float4 wb = *(const float4*)&Wl[(k + kk) * NOUT + c1];
            #pragma unroll
            for (int r = 0; r < RPT; ++r) {
                const float xs = (kk == 0) ? xv[r].x : (kk == 1) ? xv[r].y
                               : (kk == 2) ? xv[r].z : xv[r].w;
                a0[r][0] += xs * wa.x; a0[r][1] += xs * wa.y;
                a0[r][2] += xs * wa.z; a0[r][3] += xs * wa.w;
                a1[r][0] += xs * wb.x; a1[r][1] += xs * wb.y;
                a1[r][2] += xs * wb.z; a1[r][3] += xs * wb.w;
            }
        }
    }

    #pragma unroll
    for (int r = 0; r < RPT; ++r) {
        const int grow = row0 + r;
        if (grow < nrows) {
            const float dv = dinv[grow];
            float4 o0 = make_float4(a0[r][0] * dv, a0[r][1] * dv, a0[r][2] * dv, a0[r][3] * dv);
            float4 o1 = make_float4(a1[r][0] * dv, a1[r][1] * dv, a1[r][2] * dv, a1[r][3] * dv);
            *(float4*)&Y[(size_t)grow * NOUT + c0] = o0;
            *(float4*)&Y[(size_t)grow * NOUT + c1] = o1;
        }
    }
}

// Layer-1 aggregation: one wave/node; half-wave per edge (32 lanes x float4 = 512B row).
// H[v] = relu(dinv[v]*(sum_in Y[u] + Y[v]) + b)
__global__ __launch_bounds__(256) void agg_relu128(const float* __restrict__ Y,
        const int* __restrict__ rowptr, const int* __restrict__ csrc,
        const float* __restrict__ dinv, const float* __restrict__ bias,
        float* __restrict__ H, int n) {
    const int lane = threadIdx.x & 63;
    const int sub  = lane >> 5;          // half-wave id (edge parity)
    const int li   = lane & 31;          // float4 slot within row
    const int v = blockIdx.x * 4 + (threadIdx.x >> 6);
    if (v >= n) return;
    const int s = rowptr[v], e = rowptr[v + 1];
    float4 acc = make_float4(0.f, 0.f, 0.f, 0.f);
    int i = s + sub;
    for (; i + 2 < e; i += 4) {          // 2 edges per half-wave iter
        int u0 = csrc[i], u1 = csrc[i + 2];
        float4 a = *(const float4*)&Y[(size_t)u0 * 128 + li * 4];
        float4 b = *(const float4*)&Y[(size_t)u1 * 128 + li * 4];
        acc.x += a.x + b.x; acc.y += a.y + b.y;
        acc.z += a.z + b.z; acc.w += a.w + b.w;
    }
    for (; i < e; i += 2) {
        int u = csrc[i];
        float4 a = *(const float4*)&Y[(size_t)u * 128 + li * 4];
        acc.x += a.x; acc.y += a.y; acc.z += a.z; acc.w += a.w;
    }
    if (sub == 0) {                      // self-loop term once
        float4 yv = *(const float4*)&Y[(size_t)v * 128 + li * 4];
        acc.x += yv.x; acc.y += yv.y; acc.z += yv.z; acc.w += yv.w;
    }
    acc.x += __shfl_xor(acc.x, 32); acc.y += __shfl_xor(acc.y, 32);
    acc.z += __shfl_xor(acc.z, 32); acc.w += __shfl_xor(acc.w, 32);
    if (sub == 0) {
        float4 bb = *(const float4*)&bias[li * 4];
        const float dv = dinv[v];
        float4 o = make_float4(fmaxf(dv * acc.x + bb.x, 0.f),
                               fmaxf(dv * acc.y + bb.y, 0.f),
                               fmaxf(dv * acc.z + bb.z, 0.f),
                               fmaxf(dv * acc.w + bb.w, 0.f));
        *(float4*)&H[(size_t)v * 128 + li * 4] = o;
    }
}

// Layer-2 aggregation + bias + log_softmax: one wave/node; quarter-wave per edge
// (16 lanes x float4 = 256B row).
__global__ __launch_bounds__(256) void agg_lsm64(const float* __restrict__ Y2,
        const int* __restrict__ rowptr, const int* __restrict__ csrc,
        const float* __restrict__ dinv, const float* __restrict__ bias,
        float* __restrict__ out, int n) {
    const int lane = threadIdx.x & 63;
    const int q  = lane >> 4;            // quarter id (edge slot)
    const int li = lane & 15;            // float4 slot within row
    const int v = blockIdx.x * 4 + (threadIdx.x >> 6);
    if (v >= n) return;
    const int s = rowptr[v], e = rowptr[v + 1];
    float4 acc = make_float4(0.f, 0.f, 0.f, 0.f);
    int i = s + q;
    for (; i + 4 < e; i += 8) {          // 2 edges per quarter iter
        int u0 = csrc[i], u1 = csrc[i + 4];
        float4 a = *(const float4*)&Y2[(size_t)u0 * 64 + li * 4];
        float4 b = *(const float4*)&Y2[(size_t)u1 * 64 + li * 4];
        acc.x += a.x + b.x; acc.y += a.y + b.y;
        acc.z += a.z + b.z; acc.w += a.w + b.w;
    }
    for (; i < e; i += 4) {
        int u = csrc[i];
        float4 a = *(const float4*)&Y2[(size_t)u * 64 + li * 4];
        acc.x += a.x; acc.y += a.y; acc.z += a.z; acc.w += a.w;
    }
    if (q == 0) {
        float4 yv = *(const float4*)&Y2[(size_t)v * 64 + li * 4];
        acc.x += yv.x; acc.y += yv.y; acc.z += yv.z; acc.w += yv.w;
    }
    acc.x += __shfl_xor(acc.x, 16); acc.y += __shfl_xor(acc.y, 16);
    acc.z += __shfl_xor(acc.z, 16); acc.w += __shfl_xor(acc.w, 16);
    acc.x += __shfl_xor(acc.x, 32); acc.y += __shfl_xor(acc.y, 32);
    acc.z += __shfl_xor(acc.z, 32); acc.w += __shfl_xor(acc.w, 32);

    float4 bb = *(const float4*)&bias[li * 4];
    const float dv = dinv[v];
    float4 val = make_float4(dv * acc.x + bb.x, dv * acc.y + bb.y,
                             dv * acc.z + bb.z, dv * acc.w + bb.w);
    // row (64 classes) lives as 16 lanes x 4; reduce within 16-lane groups
    float m = fmaxf(fmaxf(val.x, val.y), fmaxf(val.z, val.w));
    #pragma unroll
    for (int off = 8; off >= 1; off >>= 1) m = fmaxf(m, __shfl_xor(m, off));
    float4 ex = make_float4(expf(val.x - m), expf(val.y - m),
                            expf(val.z - m), expf(val.w - m));
    float ssum = ex.x + ex.y + ex.z + ex.w;
    #pragma unroll
    for (int off = 8; off >= 1; off >>= 1) ssum += __shfl_xor(ssum, off);
    const float lse = m + logf(ssum);
    if (q == 0) {
        float4 o = make_float4(val.x - lse, val.y - lse, val.z - lse, val.w - lse);
        *(float4*)&out[(size_t)v * 64 + li * 4] = o;
    }
}

static inline size_t align_up(size_t x, size_t a) { return (x + a - 1) & ~(a - 1); }

extern "C" void kernel_launch(void* const* d_in, const int* in_sizes, int n_in,
                              void* d_out, int out_size, void* d_ws, size_t ws_size,
                              hipStream_t stream) {
    const float* x  = (const float*)d_in[0];
    const int*   ei = (const int*)d_in[1];
    const float* W1 = (const float*)d_in[2];
    const float* b1 = (const float*)d_in[3];
    const float* W2 = (const float*)d_in[4];
    const float* b2 = (const float*)d_in[5];
    float* out = (float*)d_out;

    const int N = in_sizes[0] / 128;   // 50000
    const int E = in_sizes[1] / 2;     // 800000
    const int* src = ei;
    const int* dst = ei + E;
    const int NB = (N + 1023) / 1024;  // scan blocks (49)

    // workspace layout (~56 MB)
    char* ws = (char*)d_ws;
    size_t off = 0;
    int* deg     = (int*)(ws + off); off = align_up(off + (size_t)N * 4, 512);
    int* rowptr  = (int*)(ws + off); off = align_up(off + (size_t)(N + 1) * 4, 512);
    int* fillpos = (int*)(ws + off); off = align_up(off + (size_t)N * 4, 512);
    float* dinv  = (float*)(ws + off); off = align_up(off + (size_t)N * 4, 512);
    int* bsum    = (int*)(ws + off); off = align_up(off + (size_t)NB * 4, 512);
    int* boff    = (int*)(ws + off); off = align_up(off + (size_t)NB * 4, 512);
    int* csrc    = (int*)(ws + off); off = align_up(off + (size_t)E * 4, 512);
    float* y1    = (float*)(ws + off);                 // [N,128]; reused as y2 [N,64]
    size_t off_y1 = off; off = align_up(off + (size_t)N * 128 * 4, 512);
    float* h     = (float*)(ws + off); off = align_up(off + (size_t)N * 128 * 4, 512);
    float* y2    = (float*)(ws + off_y1);
    (void)ws_size; (void)n_in; (void)out_size;

    hipMemsetAsync(deg, 0, (size_t)N * 4, stream);

    count_kernel<<<2048, 256, 0, stream>>>(dst, deg, E);
    scan_phaseA<<<NB, 256, 0, stream>>>(deg, bsum, N);
    scan_phaseB<<<1, 64, 0, stream>>>(bsum, boff, NB);
    scan_phaseC<<<NB, 256, 0, stream>>>(deg, boff, rowptr, fillpos, dinv, N);
    fill_kernel<<<2048, 256, 0, stream>>>(src, dst, fillpos, csrc, E);

    // layer 1: 64 rows/block (16 slots x RPT=4), W1 in LDS (64 KB)
    gemm_scale<128, 4><<<(N + 63) / 64, 256, 0, stream>>>(x, W1, dinv, y1, N);
    agg_relu128<<<(N + 3) / 4, 256, 0, stream>>>(y1, rowptr, csrc, dinv, b1, h, N);

    // layer 2: 64 rows/block (32 slots x RPT=2), W2 in LDS (32 KB)
    gemm_scale<64, 2><<<(N + 63) / 64, 256, 0, stream>>>(h, W2, dinv, y2, N);
    agg_lsm64<<<(N + 3) / 4, 256, 0, stream>>>(y2, rowptr, csrc, dinv, b2, out, N);
}

// Round 13
// 315.377 us; speedup vs baseline: 1.3992x; 1.0282x over previous
//
#include <hip/hip_runtime.h>
#include <hip/hip_bf16.h>

// GCN 2-layer forward. N=50000 nodes, E=800000 edges, F=128, H=128, C=64.
//   deg[v] = indeg(v)+1 ; dinv = rsqrt(deg)
//   y1 = (x @ W1) * dinv[row]
//   h  = relu(dinv[v]*(sum_{e: dst=v} y1[src] + y1[v]) + b1)
//   y2 = (h @ W2) * dinv[row]
//   o  = dinv[v]*(sum y2[src] + y2[v]) + b2 ; out = log_softmax(o)

#define K_DIM 128

// 4 edges per thread, int4 reads (E=800000 is 4-divisible; tail guarded anyway).
__global__ void count_kernel(const int* __restrict__ dst, int* __restrict__ deg, int E) {
    const int base = (blockIdx.x * blockDim.x + threadIdx.x) * 4;
    if (base + 3 < E) {
        int4 d4 = *(const int4*)&dst[base];
        atomicAdd(&deg[d4.x], 1); atomicAdd(&deg[d4.y], 1);
        atomicAdd(&deg[d4.z], 1); atomicAdd(&deg[d4.w], 1);
    } else {
        for (int j = 0; j < 4; ++j)
            if (base + j < E) atomicAdd(&deg[dst[base + j]], 1);
    }
}

// ---- 3-phase parallel exclusive scan over deg[n] (tile = 1024 elems/block) ----
__global__ __launch_bounds__(256) void scan_phaseA(const int* __restrict__ deg,
        int* __restrict__ bsum, int n) {
    const int tid = threadIdx.x, lane = tid & 63, wid = tid >> 6;
    const int base = blockIdx.x * 1024 + tid * 4;
    int s = 0;
    if (base + 3 < n) {
        int4 t = *(const int4*)&deg[base];
        s = t.x + t.y + t.z + t.w;
    } else {
        for (int j = 0; j < 4; ++j) if (base + j < n) s += deg[base + j];
    }
    #pragma unroll
    for (int off = 32; off >= 1; off >>= 1) s += __shfl_xor(s, off);
    __shared__ int wtot[4];
    if (lane == 0) wtot[wid] = s;
    __syncthreads();
    if (tid == 0) bsum[blockIdx.x] = wtot[0] + wtot[1] + wtot[2] + wtot[3];
}

__global__ __launch_bounds__(64) void scan_phaseB(const int* __restrict__ bsum,
        int* __restrict__ boff, int nb) {
    const int lane = threadIdx.x;
    int carry = 0;
    for (int base = 0; base < nb; base += 64) {
        int i = base + lane;
        int v = (i < nb) ? bsum[i] : 0;
        int s = v;
        #pragma unroll
        for (int off = 1; off < 64; off <<= 1) {
            int t = __shfl_up(s, off);
            if (lane >= off) s += t;
        }
        if (i < nb) boff[i] = carry + s - v;
        carry += __shfl(s, 63);
    }
}

__global__ __launch_bounds__(256) void scan_phaseC(const int* __restrict__ deg,
        const int* __restrict__ boff, int* __restrict__ rowptr,
        int* __restrict__ fillpos, float* __restrict__ dinv, int n) {
    const int tid = threadIdx.x, lane = tid & 63, wid = tid >> 6;
    const int base = blockIdx.x * 1024 + tid * 4;
    int v0 = 0, v1 = 0, v2 = 0, v3 = 0;
    if (base + 3 < n) {
        int4 t = *(const int4*)&deg[base];
        v0 = t.x; v1 = t.y; v2 = t.z; v3 = t.w;
    } else {
        if (base     < n) v0 = deg[base];
        if (base + 1 < n) v1 = deg[base + 1];
        if (base + 2 < n) v2 = deg[base + 2];
        if (base + 3 < n) v3 = deg[base + 3];
    }
    const int s4 = v0 + v1 + v2 + v3;
    int incl = s4;
    #pragma unroll
    for (int off = 1; off < 64; off <<= 1) {
        int t = __shfl_up(incl, off);
        if (lane >= off) incl += t;
    }
    __shared__ int wtot[4];
    if (lane == 63) wtot[wid] = incl;
    __syncthreads();
    int wexc = 0;
    #pragma unroll
    for (int w = 0; w < 4; ++w) if (w < wid) wexc += wtot[w];

    const int ex = boff[blockIdx.x] + wexc + (incl - s4);
    if (blockIdx.x == 0 && tid == 0) rowptr[0] = 0;
    const int p1 = ex + v0, p2 = p1 + v1, p3 = p2 + v2, p4 = p3 + v3;
    if (base < n)     { fillpos[base]     = ex; rowptr[base + 1] = p1; dinv[base]     = rsqrtf((float)(v0 + 1)); }
    if (base + 1 < n) { fillpos[base + 1] = p1; rowptr[base + 2] = p2; dinv[base + 1] = rsqrtf((float)(v1 + 1)); }
    if (base + 2 < n) { fillpos[base + 2] = p2; rowptr[base + 3] = p3; dinv[base + 2] = rsqrtf((float)(v2 + 1)); }
    if (base + 3 < n) { fillpos[base + 3] = p3; rowptr[base + 4] = p4; dinv[base + 3] = rsqrtf((float)(v3 + 1)); }
}

// 4 edges per thread, int4 reads of src/dst.
__global__ void fill_kernel(const int* __restrict__ src, const int* __restrict__ dst,
                            int* __restrict__ fillpos, int* __restrict__ csrc, int E) {
    const int base = (blockIdx.x * blockDim.x + threadIdx.x) * 4;
    if (base + 3 < E) {
        int4 s4 = *(const int4*)&src[base];
        int4 d4 = *(const int4*)&dst[base];
        csrc[atomicAdd(&fillpos[d4.x], 1)] = s4.x;
        csrc[atomicAdd(&fillpos[d4.y], 1)] = s4.y;
        csrc[atomicAdd(&fillpos[d4.z], 1)] = s4.z;
        csrc[atomicAdd(&fillpos[d4.w], 1)] = s4.w;
    } else {
        for (int j = 0; j < 4; ++j)
            if (base + j < E) csrc[atomicAdd(&fillpos[dst[base + j]], 1)] = src[base + j];
    }
}

// Y[row] = (X[row] @ W) * dinv[row].
// W [K][NOUT] staged in LDS (0.5 B LDS per FLOP); X global with wave broadcast.
template<int NOUT, int RPT>
__global__ __launch_bounds__(256) void gemm_scale(const float* __restrict__ X,
        const float* __restrict__ W, const float* __restrict__ dinv,
        float* __restrict__ Y, int nrows) {
    constexpr int K     = K_DIM;
    constexpr int CG    = NOUT / 8;       // col groups (8 cols per thread)
    constexpr int SLOTS = 256 / CG;       // row slots per block
    constexpr int ROWS  = SLOTS * RPT;    // rows per block
    constexpr int HALF  = NOUT / 2;
    __shared__ float Wl[K * NOUT];
    const int tid = threadIdx.x;

    #pragma unroll
    for (int i = tid * 4; i < K * NOUT; i += 1024)
        *(float4*)&Wl[i] = *(const float4*)&W[i];
    __syncthreads();

    const int cg = tid % CG, slot = tid / CG;
    const int c0 = cg * 4, c1 = c0 + HALF;
    const int row0 = blockIdx.x * ROWS + slot * RPT;

    int rIdx[RPT];
    #pragma unroll
    for (int r = 0; r < RPT; ++r) rIdx[r] = min(row0 + r, nrows - 1);

    float a0[RPT][4], a1[RPT][4];
    #pragma unroll
    for (int r = 0; r < RPT; ++r)
        #pragma unroll
        for (int c = 0; c < 4; ++c) { a0[r][c] = 0.f; a1[r][c] = 0.f; }

    #pragma unroll 2
    for (int k = 0; k < K; k += 4) {
        float4 xv[RPT];
        #pragma unroll
        for (int r = 0; r < RPT; ++r)
            xv[r] = *(const float4*)&X[(size_t)rIdx[r] * K + k];
        #pragma unroll
        for (int kk = 0; kk < 4; ++kk) {
            float4 wa = *(const float4*)&Wl[(k + kk) * NOUT + c0];
            float4 wb = *(const float4*)&Wl[(k + kk) * NOUT + c1];
            #pragma unroll
            for (int r = 0; r < RPT; ++r) {
                const float xs = (kk == 0) ? xv[r].x : (kk == 1) ? xv[r].y
                               : (kk == 2) ? xv[r].z : xv[r].w;
                a0[r][0] += xs * wa.x; a0[r][1] += xs * wa.y;
                a0[r][2] += xs * wa.z; a0[r][3] += xs * wa.w;
                a1[r][0] += xs * wb.x; a1[r][1] += xs * wb.y;
                a1[r][2] += xs * wb.z; a1[r][3] += xs * wb.w;
            }
        }
    }

    #pragma unroll
    for (int r = 0; r < RPT; ++r) {
        const int grow = row0 + r;
        if (grow < nrows) {
            const float dv = dinv[grow];
            float4 o0 = make_float4(a0[r][0] * dv, a0[r][1] * dv, a0[r][2] * dv, a0[r][3] * dv);
            float4 o1 = make_float4(a1[r][0] * dv, a1[r][1] * dv, a1[r][2] * dv, a1[r][3] * dv);
            *(float4*)&Y[(size_t)grow * NOUT + c0] = o0;
            *(float4*)&Y[(size_t)grow * NOUT + c1] = o1;
        }
    }
}

// Layer-1 aggregation: one wave/node; half-wave per edge (32 lanes x float4 = 512B).
// 4 edges in flight per half-wave iteration (MLP for L3-latency hiding).
__global__ __launch_bounds__(256) void agg_relu128(const float* __restrict__ Y,
        const int* __restrict__ rowptr, const int* __restrict__ csrc,
        const float* __restrict__ dinv, const float* __restrict__ bias,
        float* __restrict__ H, int n) {
    const int lane = threadIdx.x & 63;
    const int sub  = lane >> 5;          // half-wave id (edge parity)
    const int li   = lane & 31;          // float4 slot within row
    const int v = blockIdx.x * 4 + (threadIdx.x >> 6);
    if (v >= n) return;
    const int s = rowptr[v], e = rowptr[v + 1];
    float4 acc = make_float4(0.f, 0.f, 0.f, 0.f);
    int i = s + sub;
    for (; i + 6 < e; i += 8) {          // 4 edges per half-wave iter
        int u0 = csrc[i], u1 = csrc[i + 2], u2 = csrc[i + 4], u3 = csrc[i + 6];
        float4 a = *(const float4*)&Y[(size_t)u0 * 128 + li * 4];
        float4 b = *(const float4*)&Y[(size_t)u1 * 128 + li * 4];
        float4 c = *(const float4*)&Y[(size_t)u2 * 128 + li * 4];
        float4 d = *(const float4*)&Y[(size_t)u3 * 128 + li * 4];
        acc.x += (a.x + b.x) + (c.x + d.x);
        acc.y += (a.y + b.y) + (c.y + d.y);
        acc.z += (a.z + b.z) + (c.z + d.z);
        acc.w += (a.w + b.w) + (c.w + d.w);
    }
    for (; i < e; i += 2) {
        int u = csrc[i];
        float4 a = *(const float4*)&Y[(size_t)u * 128 + li * 4];
        acc.x += a.x; acc.y += a.y; acc.z += a.z; acc.w += a.w;
    }
    if (sub == 0) {                      // self-loop term once
        float4 yv = *(const float4*)&Y[(size_t)v * 128 + li * 4];
        acc.x += yv.x; acc.y += yv.y; acc.z += yv.z; acc.w += yv.w;
    }
    acc.x += __shfl_xor(acc.x, 32); acc.y += __shfl_xor(acc.y, 32);
    acc.z += __shfl_xor(acc.z, 32); acc.w += __shfl_xor(acc.w, 32);
    if (sub == 0) {
        float4 bb = *(const float4*)&bias[li * 4];
        const float dv = dinv[v];
        float4 o = make_float4(fmaxf(dv * acc.x + bb.x, 0.f),
                               fmaxf(dv * acc.y + bb.y, 0.f),
                               fmaxf(dv * acc.z + bb.z, 0.f),
                               fmaxf(dv * acc.w + bb.w, 0.f));
        *(float4*)&H[(size_t)v * 128 + li * 4] = o;
    }
}

// Layer-2 aggregation + bias + log_softmax: one wave/node; quarter-wave per edge
// (16 lanes x float4 = 256B row); 4 edges in flight per quarter iteration.
__global__ __launch_bounds__(256) void agg_lsm64(const float* __restrict__ Y2,
        const int* __restrict__ rowptr, const int* __restrict__ csrc,
        const float* __restrict__ dinv, const float* __restrict__ bias,
        float* __restrict__ out, int n) {
    const int lane = threadIdx.x & 63;
    const int q  = lane >> 4;            // quarter id (edge slot)
    const int li = lane & 15;            // float4 slot within row
    const int v = blockIdx.x * 4 + (threadIdx.x >> 6);
    if (v >= n) return;
    const int s = rowptr[v], e = rowptr[v + 1];
    float4 acc = make_float4(0.f, 0.f, 0.f, 0.f);
    int i = s + q;
    for (; i + 12 < e; i += 16) {        // 4 edges per quarter iter
        int u0 = csrc[i], u1 = csrc[i + 4], u2 = csrc[i + 8], u3 = csrc[i + 12];
        float4 a = *(const float4*)&Y2[(size_t)u0 * 64 + li * 4];
        float4 b = *(const float4*)&Y2[(size_t)u1 * 64 + li * 4];
        float4 c = *(const float4*)&Y2[(size_t)u2 * 64 + li * 4];
        float4 d = *(const float4*)&Y2[(size_t)u3 * 64 + li * 4];
        acc.x += (a.x + b.x) + (c.x + d.x);
        acc.y += (a.y + b.y) + (c.y + d.y);
        acc.z += (a.z + b.z) + (c.z + d.z);
        acc.w += (a.w + b.w) + (c.w + d.w);
    }
    for (; i < e; i += 4) {
        int u = csrc[i];
        float4 a = *(const float4*)&Y2[(size_t)u * 64 + li * 4];
        acc.x += a.x; acc.y += a.y; acc.z += a.z; acc.w += a.w;
    }
    if (q == 0) {
        float4 yv = *(const float4*)&Y2[(size_t)v * 64 + li * 4];
        acc.x += yv.x; acc.y += yv.y; acc.z += yv.z; acc.w += yv.w;
    }
    acc.x += __shfl_xor(acc.x, 16); acc.y += __shfl_xor(acc.y, 16);
    acc.z += __shfl_xor(acc.z, 16); acc.w += __shfl_xor(acc.w, 16);
    acc.x += __shfl_xor(acc.x, 32); acc.y += __shfl_xor(acc.y, 32);
    acc.z += __shfl_xor(acc.z, 32); acc.w += __shfl_xor(acc.w, 32);

    float4 bb = *(const float4*)&bias[li * 4];
    const float dv = dinv[v];
    float4 val = make_float4(dv * acc.x + bb.x, dv * acc.y + bb.y,
                             dv * acc.z + bb.z, dv * acc.w + bb.w);
    // row (64 classes) lives as 16 lanes x 4; reduce within 16-lane groups
    float m = fmaxf(fmaxf(val.x, val.y), fmaxf(val.z, val.w));
    #pragma unroll
    for (int off = 8; off >= 1; off >>= 1) m = fmaxf(m, __shfl_xor(m, off));
    float4 ex = make_float4(expf(val.x - m), expf(val.y - m),
                            expf(val.z - m), expf(val.w - m));
    float ssum = ex.x + ex.y + ex.z + ex.w;
    #pragma unroll
    for (int off = 8; off >= 1; off >>= 1) ssum += __shfl_xor(ssum, off);
    const float lse = m + logf(ssum);
    if (q == 0) {
        float4 o = make_float4(val.x - lse, val.y - lse, val.z - lse, val.w - lse);
        *(float4*)&out[(size_t)v * 64 + li * 4] = o;
    }
}

static inline size_t align_up(size_t x, size_t a) { return (x + a - 1) & ~(a - 1); }

extern "C" void kernel_launch(void* const* d_in, const int* in_sizes, int n_in,
                              void* d_out, int out_size, void* d_ws, size_t ws_size,
                              hipStream_t stream) {
    const float* x  = (const float*)d_in[0];
    const int*   ei = (const int*)d_in[1];
    const float* W1 = (const float*)d_in[2];
    const float* b1 = (const float*)d_in[3];
    const float* W2 = (const float*)d_in[4];
    const float* b2 = (const float*)d_in[5];
    float* out = (float*)d_out;

    const int N = in_sizes[0] / 128;   // 50000
    const int E = in_sizes[1] / 2;     // 800000
    const int* src = ei;
    const int* dst = ei + E;
    const int NB = (N + 1023) / 1024;  // scan blocks (49)
    const int EB4 = (E / 4 + 255) / 256;  // edge blocks, 4 edges/thread

    // workspace layout (~56 MB)
    char* ws = (char*)d_ws;
    size_t off = 0;
    int* deg     = (int*)(ws + off); off = align_up(off + (size_t)N * 4, 512);
    int* rowptr  = (int*)(ws + off); off = align_up(off + (size_t)(N + 1) * 4, 512);
    int* fillpos = (int*)(ws + off); off = align_up(off + (size_t)N * 4, 512);
    float* dinv  = (float*)(ws + off); off = align_up(off + (size_t)N * 4, 512);
    int* bsum    = (int*)(ws + off); off = align_up(off + (size_t)NB * 4, 512);
    int* boff    = (int*)(ws + off); off = align_up(off + (size_t)NB * 4, 512);
    int* csrc    = (int*)(ws + off); off = align_up(off + (size_t)E * 4, 512);
    float* y1    = (float*)(ws + off);                 // [N,128]; reused as y2 [N,64]
    size_t off_y1 = off; off = align_up(off + (size_t)N * 128 * 4, 512);
    float* h     = (float*)(ws + off); off = align_up(off + (size_t)N * 128 * 4, 512);
    float* y2    = (float*)(ws + off_y1);
    (void)ws_size; (void)n_in; (void)out_size;

    hipMemsetAsync(deg, 0, (size_t)N * 4, stream);

    count_kernel<<<EB4, 256, 0, stream>>>(dst, deg, E);
    scan_phaseA<<<NB, 256, 0, stream>>>(deg, bsum, N);
    scan_phaseB<<<1, 64, 0, stream>>>(bsum, boff, NB);
    scan_phaseC<<<NB, 256, 0, stream>>>(deg, boff, rowptr, fillpos, dinv, N);
    fill_kernel<<<EB4, 256, 0, stream>>>(src, dst, fillpos, csrc, E);

    // layer 1: 64 rows/block (16 slots x RPT=4), W1 in LDS (64 KB)
    gemm_scale<128, 4><<<(N + 63) / 64, 256, 0, stream>>>(x, W1, dinv, y1, N);
    agg_relu128<<<(N + 3) / 4, 256, 0, stream>>>(y1, rowptr, csrc, dinv, b1, h, N);

    // layer 2: 64 rows/block (32 slots x RPT=2), W2 in LDS (32 KB)
    gemm_scale<64, 2><<<(N + 63) / 64, 256, 0, stream>>>(h, W2, dinv, y2, N);
    agg_lsm64<<<(N + 3) / 4, 256, 0, stream>>>(y2, rowptr, csrc, dinv, b2, out, N);
}

// Round 15
// 295.560 us; speedup vs baseline: 1.4930x; 1.0670x over previous
//
#include <hip/hip_runtime.h>
#include <hip/hip_bf16.h>

// GCN 2-layer forward. N=50000 nodes, E=800000 edges, F=128, H=128, C=64.
//   deg[v] = indeg(v)+1 ; dinv = rsqrt(deg)
//   y1 = (x @ W1) * dinv[row]          [stored bf16: gather operand, BW-bound]
//   h  = relu(dinv[v]*(sum_{e: dst=v} y1[src] + y1[v]) + b1)   [fp32]
//   y2 = (h @ W2) * dinv[row]          [fp32]
//   o  = dinv[v]*(sum y2[src] + y2[v]) + b2 ; out = log_softmax(o)

#define K_DIM 128

__device__ __forceinline__ ushort f2bf(float f) {          // round-to-nearest-even
    unsigned u = __float_as_uint(f);
    return (ushort)((u + 0x7FFF + ((u >> 16) & 1)) >> 16);
}
__device__ __forceinline__ float bflo(unsigned p) { return __uint_as_float(p << 16); }
__device__ __forceinline__ float bfhi(unsigned p) { return __uint_as_float(p & 0xFFFF0000u); }

// 4 edges per thread, int4 reads.
__global__ void count_kernel(const int* __restrict__ dst, int* __restrict__ deg, int E) {
    const int base = (blockIdx.x * blockDim.x + threadIdx.x) * 4;
    if (base + 3 < E) {
        int4 d4 = *(const int4*)&dst[base];
        atomicAdd(&deg[d4.x], 1); atomicAdd(&deg[d4.y], 1);
        atomicAdd(&deg[d4.z], 1); atomicAdd(&deg[d4.w], 1);
    } else {
        for (int j = 0; j < 4; ++j)
            if (base + j < E) atomicAdd(&deg[dst[base + j]], 1);
    }
}

// ---- 3-phase parallel exclusive scan over deg[n] ----
__global__ __launch_bounds__(256) void scan_phaseA(const int* __restrict__ deg,
        int* __restrict__ bsum, int n) {
    const int tid = threadIdx.x, lane = tid & 63, wid = tid >> 6;
    const int base = blockIdx.x * 1024 + tid * 4;
    int s = 0;
    if (base + 3 < n) {
        int4 t = *(const int4*)&deg[base];
        s = t.x + t.y + t.z + t.w;
    } else {
        for (int j = 0; j < 4; ++j) if (base + j < n) s += deg[base + j];
    }
    #pragma unroll
    for (int off = 32; off >= 1; off >>= 1) s += __shfl_xor(s, off);
    __shared__ int wtot[4];
    if (lane == 0) wtot[wid] = s;
    __syncthreads();
    if (tid == 0) bsum[blockIdx.x] = wtot[0] + wtot[1] + wtot[2] + wtot[3];
}

__global__ __launch_bounds__(64) void scan_phaseB(const int* __restrict__ bsum,
        int* __restrict__ boff, int nb) {
    const int lane = threadIdx.x;
    int carry = 0;
    for (int base = 0; base < nb; base += 64) {
        int i = base + lane;
        int v = (i < nb) ? bsum[i] : 0;
        int s = v;
        #pragma unroll
        for (int off = 1; off < 64; off <<= 1) {
            int t = __shfl_up(s, off);
            if (lane >= off) s += t;
        }
        if (i < nb) boff[i] = carry + s - v;
        carry += __shfl(s, 63);
    }
}

__global__ __launch_bounds__(256) void scan_phaseC(const int* __restrict__ deg,
        const int* __restrict__ boff, int* __restrict__ rowptr,
        int* __restrict__ fillpos, float* __restrict__ dinv, int n) {
    const int tid = threadIdx.x, lane = tid & 63, wid = tid >> 6;
    const int base = blockIdx.x * 1024 + tid * 4;
    int v0 = 0, v1 = 0, v2 = 0, v3 = 0;
    if (base + 3 < n) {
        int4 t = *(const int4*)&deg[base];
        v0 = t.x; v1 = t.y; v2 = t.z; v3 = t.w;
    } else {
        if (base     < n) v0 = deg[base];
        if (base + 1 < n) v1 = deg[base + 1];
        if (base + 2 < n) v2 = deg[base + 2];
        if (base + 3 < n) v3 = deg[base + 3];
    }
    const int s4 = v0 + v1 + v2 + v3;
    int incl = s4;
    #pragma unroll
    for (int off = 1; off < 64; off <<= 1) {
        int t = __shfl_up(incl, off);
        if (lane >= off) incl += t;
    }
    __shared__ int wtot[4];
    if (lane == 63) wtot[wid] = incl;
    __syncthreads();
    int wexc = 0;
    #pragma unroll
    for (int w = 0; w < 4; ++w) if (w < wid) wexc += wtot[w];

    const int ex = boff[blockIdx.x] + wexc + (incl - s4);
    if (blockIdx.x == 0 && tid == 0) rowptr[0] = 0;
    const int p1 = ex + v0, p2 = p1 + v1, p3 = p2 + v2, p4 = p3 + v3;
    if (base < n)     { fillpos[base]     = ex; rowptr[base + 1] = p1; dinv[base]     = rsqrtf((float)(v0 + 1)); }
    if (base + 1 < n) { fillpos[base + 1] = p1; rowptr[base + 2] = p2; dinv[base + 1] = rsqrtf((float)(v1 + 1)); }
    if (base + 2 < n) { fillpos[base + 2] = p2; rowptr[base + 3] = p3; dinv[base + 2] = rsqrtf((float)(v2 + 1)); }
    if (base + 3 < n) { fillpos[base + 3] = p3; rowptr[base + 4] = p4; dinv[base + 3] = rsqrtf((float)(v3 + 1)); }
}

// 4 edges per thread, int4 reads of src/dst.
__global__ void fill_kernel(const int* __restrict__ src, const int* __restrict__ dst,
                            int* __restrict__ fillpos, int* __restrict__ csrc, int E) {
    const int base = (blockIdx.x * blockDim.x + threadIdx.x) * 4;
    if (base + 3 < E) {
        int4 s4 = *(const int4*)&src[base];
        int4 d4 = *(const int4*)&dst[base];
        csrc[atomicAdd(&fillpos[d4.x], 1)] = s4.x;
        csrc[atomicAdd(&fillpos[d4.y], 1)] = s4.y;
        csrc[atomicAdd(&fillpos[d4.z], 1)] = s4.z;
        csrc[atomicAdd(&fillpos[d4.w], 1)] = s4.w;
    } else {
        for (int j = 0; j < 4; ++j)
            if (base + j < E) csrc[atomicAdd(&fillpos[dst[base + j]], 1)] = src[base + j];
    }
}

// Y[row] = (X[row] @ W) * dinv[row]; output fp32 or bf16 per template flag.
template<int NOUT, int RPT, bool BF16_OUT>
__global__ __launch_bounds__(256) void gemm_scale(const float* __restrict__ X,
        const float* __restrict__ W, const float* __restrict__ dinv,
        void* __restrict__ Yout, int nrows) {
    constexpr int K     = K_DIM;
    constexpr int CG    = NOUT / 8;       // col groups (8 cols per thread)
    constexpr int SLOTS = 256 / CG;       // row slots per block
    constexpr int ROWS  = SLOTS * RPT;    // rows per block
    constexpr int HALF  = NOUT / 2;
    __shared__ float Wl[K * NOUT];
    const int tid = threadIdx.x;

    #pragma unroll
    for (int i = tid * 4; i < K * NOUT; i += 1024)
        *(float4*)&Wl[i] = *(const float4*)&W[i];
    __syncthreads();

    const int cg = tid % CG, slot = tid / CG;
    const int c0 = cg * 4, c1 = c0 + HALF;
    const int row0 = blockIdx.x * ROWS + slot * RPT;

    int rIdx[RPT];
    #pragma unroll
    for (int r = 0; r < RPT; ++r) rIdx[r] = min(row0 + r, nrows - 1);

    float a0[RPT][4], a1[RPT][4];
    #pragma unroll
    for (int r = 0; r < RPT; ++r)
        #pragma unroll
        for (int c = 0; c < 4; ++c) { a0[r][c] = 0.f; a1[r][c] = 0.f; }

    #pragma unroll 2
    for (int k = 0; k < K; k += 4) {
        float4 xv[RPT];
        #pragma unroll
        for (int r = 0; r < RPT; ++r)
            xv[r] = *(const float4*)&X[(size_t)rIdx[r] * K + k];
        #pragma unroll
        for (int kk = 0; kk < 4; ++kk) {
            float4 wa = *(const float4*)&Wl[(k + kk) * NOUT + c0];
            float4 wb = *(const float4*)&Wl[(k + kk) * NOUT + c1];
            #pragma unroll
            for (int r = 0; r < RPT; ++r) {
                const float xs = (kk == 0) ? xv[r].x : (kk == 1) ? xv[r].y
                               : (kk == 2) ? xv[r].z : xv[r].w;
                a0[r][0] += xs * wa.x; a0[r][1] += xs * wa.y;
                a0[r][2] += xs * wa.z; a0[r][3] += xs * wa.w;
                a1[r][0] += xs * wb.x; a1[r][1] += xs * wb.y;
                a1[r][2] += xs * wb.z; a1[r][3] += xs * wb.w;
            }
        }
    }

    #pragma unroll
    for (int r = 0; r < RPT; ++r) {
        const int grow = row0 + r;
        if (grow < nrows) {
            const float dv = dinv[grow];
            if constexpr (BF16_OUT) {
                ushort* Yb = (ushort*)Yout;
                ushort4 o0, o1;
                o0.x = f2bf(a0[r][0] * dv); o0.y = f2bf(a0[r][1] * dv);
                o0.z = f2bf(a0[r][2] * dv); o0.w = f2bf(a0[r][3] * dv);
                o1.x = f2bf(a1[r][0] * dv); o1.y = f2bf(a1[r][1] * dv);
                o1.z = f2bf(a1[r][2] * dv); o1.w = f2bf(a1[r][3] * dv);
                *(ushort4*)&Yb[(size_t)grow * NOUT + c0] = o0;
                *(ushort4*)&Yb[(size_t)grow * NOUT + c1] = o1;
            } else {
                float* Yf = (float*)Yout;
                float4 o0 = make_float4(a0[r][0] * dv, a0[r][1] * dv, a0[r][2] * dv, a0[r][3] * dv);
                float4 o1 = make_float4(a1[r][0] * dv, a1[r][1] * dv, a1[r][2] * dv, a1[r][3] * dv);
                *(float4*)&Yf[(size_t)grow * NOUT + c0] = o0;
                *(float4*)&Yf[(size_t)grow * NOUT + c1] = o1;
            }
        }
    }
}

// Layer-1 aggregation over bf16 y1: one wave/node; quarter-wave per edge
// (16 lanes x 16B uint4 = one 256B bf16 row); 2 edges unrolled per quarter.
// H[v] = relu(dinv[v]*(sum_in Y[u] + Y[v]) + b)   (H stays fp32)
__global__ __launch_bounds__(256) void agg_relu128(const ushort* __restrict__ Yb,
        const int* __restrict__ rowptr, const int* __restrict__ csrc,
        const float* __restrict__ dinv, const float* __restrict__ bias,
        float* __restrict__ H, int n) {
    const int lane = threadIdx.x & 63;
    const int q  = lane >> 4;            // quarter id (edge slot)
    const int li = lane & 15;            // 8-bf16 (16B) slot within row
    const int v = blockIdx.x * 4 + (threadIdx.x >> 6);
    if (v >= n) return;
    const int s = rowptr[v], e = rowptr[v + 1];
    float acc[8];
    #pragma unroll
    for (int j = 0; j < 8; ++j) acc[j] = 0.f;

    int i = s + q;
    for (; i + 4 < e; i += 8) {          // 2 edges per quarter iter (8/wave in flight)
        int u0 = csrc[i], u1 = csrc[i + 4];
        uint4 wa = *(const uint4*)&Yb[(size_t)u0 * 128 + li * 8];
        uint4 wb = *(const uint4*)&Yb[(size_t)u1 * 128 + li * 8];
        acc[0] += bflo(wa.x) + bflo(wb.x); acc[1] += bfhi(wa.x) + bfhi(wb.x);
        acc[2] += bflo(wa.y) + bflo(wb.y); acc[3] += bfhi(wa.y) + bfhi(wb.y);
        acc[4] += bflo(wa.z) + bflo(wb.z); acc[5] += bfhi(wa.z) + bfhi(wb.z);
        acc[6] += bflo(wa.w) + bflo(wb.w); acc[7] += bfhi(wa.w) + bfhi(wb.w);
    }
    for (; i < e; i += 4) {
        int u = csrc[i];
        uint4 wa = *(const uint4*)&Yb[(size_t)u * 128 + li * 8];
        acc[0] += bflo(wa.x); acc[1] += bfhi(wa.x);
        acc[2] += bflo(wa.y); acc[3] += bfhi(wa.y);
        acc[4] += bflo(wa.z); acc[5] += bfhi(wa.z);
        acc[6] += bflo(wa.w); acc[7] += bfhi(wa.w);
    }
    if (q == 0) {                        // self-loop term once
        uint4 wv = *(const uint4*)&Yb[(size_t)v * 128 + li * 8];
        acc[0] += bflo(wv.x); acc[1] += bfhi(wv.x);
        acc[2] += bflo(wv.y); acc[3] += bfhi(wv.y);
        acc[4] += bflo(wv.z); acc[5] += bfhi(wv.z);
        acc[6] += bflo(wv.w); acc[7] += bfhi(wv.w);
    }
    #pragma unroll
    for (int j = 0; j < 8; ++j) {
        acc[j] += __shfl_xor(acc[j], 16);
        acc[j] += __shfl_xor(acc[j], 32);
    }
    if (q == 0) {
        float4 b0 = *(const float4*)&bias[li * 8];
        float4 b1 = *(const float4*)&bias[li * 8 + 4];
        const float dv = dinv[v];
        float4 o0 = make_float4(fmaxf(dv * acc[0] + b0.x, 0.f),
                                fmaxf(dv * acc[1] + b0.y, 0.f),
                                fmaxf(dv * acc[2] + b0.z, 0.f),
                                fmaxf(dv * acc[3] + b0.w, 0.f));
        float4 o1 = make_float4(fmaxf(dv * acc[4] + b1.x, 0.f),
                                fmaxf(dv * acc[5] + b1.y, 0.f),
                                fmaxf(dv * acc[6] + b1.z, 0.f),
                                fmaxf(dv * acc[7] + b1.w, 0.f));
        *(float4*)&H[(size_t)v * 128 + li * 8] = o0;
        *(float4*)&H[(size_t)v * 128 + li * 8 + 4] = o1;
    }
}

// Layer-2 aggregation + bias + log_softmax (y2 fp32): quarter-wave per edge,
// 4 edges in flight per quarter iteration.
__global__ __launch_bounds__(256) void agg_lsm64(const float* __restrict__ Y2,
        const int* __restrict__ rowptr, const int* __restrict__ csrc,
        const float* __restrict__ dinv, const float* __restrict__ bias,
        float* __restrict__ out, int n) {
    const int lane = threadIdx.x & 63;
    const int q  = lane >> 4;            // quarter id (edge slot)
    const int li = lane & 15;            // float4 slot within row
    const int v = blockIdx.x * 4 + (threadIdx.x >> 6);
    if (v >= n) return;
    const int s = rowptr[v], e = rowptr[v + 1];
    float4 acc = make_float4(0.f, 0.f, 0.f, 0.f);
    int i = s + q;
    for (; i + 12 < e; i += 16) {        // 4 edges per quarter iter
        int u0 = csrc[i], u1 = csrc[i + 4], u2 = csrc[i + 8], u3 = csrc[i + 12];
        float4 a = *(const float4*)&Y2[(size_t)u0 * 64 + li * 4];
        float4 b = *(const float4*)&Y2[(size_t)u1 * 64 + li * 4];
        float4 c = *(const float4*)&Y2[(size_t)u2 * 64 + li * 4];
        float4 d = *(const float4*)&Y2[(size_t)u3 * 64 + li * 4];
        acc.x += (a.x + b.x) + (c.x + d.x);
        acc.y += (a.y + b.y) + (c.y + d.y);
        acc.z += (a.z + b.z) + (c.z + d.z);
        acc.w += (a.w + b.w) + (c.w + d.w);
    }
    for (; i < e; i += 4) {
        int u = csrc[i];
        float4 a = *(const float4*)&Y2[(size_t)u * 64 + li * 4];
        acc.x += a.x; acc.y += a.y; acc.z += a.z; acc.w += a.w;
    }
    if (q == 0) {
        float4 yv = *(const float4*)&Y2[(size_t)v * 64 + li * 4];
        acc.x += yv.x; acc.y += yv.y; acc.z += yv.z; acc.w += yv.w;
    }
    acc.x += __shfl_xor(acc.x, 16); acc.y += __shfl_xor(acc.y, 16);
    acc.z += __shfl_xor(acc.z, 16); acc.w += __shfl_xor(acc.w, 16);
    acc.x += __shfl_xor(acc.x, 32); acc.y += __shfl_xor(acc.y, 32);
    acc.z += __shfl_xor(acc.z, 32); acc.w += __shfl_xor(acc.w, 32);

    float4 bb = *(const float4*)&bias[li * 4];
    const float dv = dinv[v];
    float4 val = make_float4(dv * acc.x + bb.x, dv * acc.y + bb.y,
                             dv * acc.z + bb.z, dv * acc.w + bb.w);
    float m = fmaxf(fmaxf(val.x, val.y), fmaxf(val.z, val.w));
    #pragma unroll
    for (int off = 8; off >= 1; off >>= 1) m = fmaxf(m, __shfl_xor(m, off));
    float4 ex = make_float4(expf(val.x - m), expf(val.y - m),
                            expf(val.z - m), expf(val.w - m));
    float ssum = ex.x + ex.y + ex.z + ex.w;
    #pragma unroll
    for (int off = 8; off >= 1; off >>= 1) ssum += __shfl_xor(ssum, off);
    const float lse = m + logf(ssum);
    if (q == 0) {
        float4 o = make_float4(val.x - lse, val.y - lse, val.z - lse, val.w - lse);
        *(float4*)&out[(size_t)v * 64 + li * 4] = o;
    }
}

static inline size_t align_up(size_t x, size_t a) { return (x + a - 1) & ~(a - 1); }

extern "C" void kernel_launch(void* const* d_in, const int* in_sizes, int n_in,
                              void* d_out, int out_size, void* d_ws, size_t ws_size,
                              hipStream_t stream) {
    const float* x  = (const float*)d_in[0];
    const int*   ei = (const int*)d_in[1];
    const float* W1 = (const float*)d_in[2];
    const float* b1 = (const float*)d_in[3];
    const float* W2 = (const float*)d_in[4];
    const float* b2 = (const float*)d_in[5];
    float* out = (float*)d_out;

    const int N = in_sizes[0] / 128;   // 50000
    const int E = in_sizes[1] / 2;     // 800000
    const int* src = ei;
    const int* dst = ei + E;
    const int NB = (N + 1023) / 1024;  // scan blocks (49)
    const int EB4 = (E / 4 + 255) / 256;  // edge blocks, 4 edges/thread

    // workspace layout (~56 MB; y1 region kept at fp32 size for safety)
    char* ws = (char*)d_ws;
    size_t off = 0;
    int* deg     = (int*)(ws + off); off = align_up(off + (size_t)N * 4, 512);
    int* rowptr  = (int*)(ws + off); off = align_up(off + (size_t)(N + 1) * 4, 512);
    int* fillpos = (int*)(ws + off); off = align_up(off + (size_t)N * 4, 512);
    float* dinv  = (float*)(ws + off); off = align_up(off + (size_t)N * 4, 512);
    int* bsum    = (int*)(ws + off); off = align_up(off + (size_t)NB * 4, 512);
    int* boff    = (int*)(ws + off); off = align_up(off + (size_t)NB * 4, 512);
    int* csrc    = (int*)(ws + off); off = align_up(off + (size_t)E * 4, 512);
    ushort* y1   = (ushort*)(ws + off);                // [N,128] bf16; region reused as y2 fp32 [N,64]
    size_t off_y1 = off; off = align_up(off + (size_t)N * 128 * 4, 512);
    float* h     = (float*)(ws + off); off = align_up(off + (size_t)N * 128 * 4, 512);
    float* y2    = (float*)(ws + off_y1);
    (void)ws_size; (void)n_in; (void)out_size;

    hipMemsetAsync(deg, 0, (size_t)N * 4, stream);

    count_kernel<<<EB4, 256, 0, stream>>>(dst, deg, E);
    scan_phaseA<<<NB, 256, 0, stream>>>(deg, bsum, N);
    scan_phaseB<<<1, 64, 0, stream>>>(bsum, boff, NB);
    scan_phaseC<<<NB, 256, 0, stream>>>(deg, boff, rowptr, fillpos, dinv, N);
    fill_kernel<<<EB4, 256, 0, stream>>>(src, dst, fillpos, csrc, E);

    // layer 1: gemm writes bf16 y1; aggregation gathers bf16
    gemm_scale<128, 4, true><<<(N + 63) / 64, 256, 0, stream>>>(x, W1, dinv, (void*)y1, N);
    agg_relu128<<<(N + 3) / 4, 256, 0, stream>>>(y1, rowptr, csrc, dinv, b1, h, N);

    // layer 2: fp32 throughout
    gemm_scale<64, 2, false><<<(N + 63) / 64, 256, 0, stream>>>(h, W2, dinv, (void*)y2, N);
    agg_lsm64<<<(N + 3) / 4, 256, 0, stream>>>(y2, rowptr, csrc, dinv, b2, out, N);
}